// Round 14
// baseline (119.375 us; speedup 1.0000x reference)
//
#include <hip/hip_runtime.h>

#define MTOK 8192   // B*S tokens
#define ED   1024   // E == D == 1024

typedef short s16x8 __attribute__((ext_vector_type(8)));
typedef float f32x4 __attribute__((ext_vector_type(4)));
typedef int   i32x4 __attribute__((ext_vector_type(4)));
typedef unsigned short u16x4 __attribute__((ext_vector_type(4)));

__device__ __forceinline__ int cvtpk(float a, float b) {
    int r;
    asm("v_cvt_pk_bf16_f32 %0, %1, %2" : "=v"(r) : "v"(a), "v"(b));
    return r;
}

// 8 fp32 -> 8 bf16 hi + 8 bf16 lo (exact residual), register form
__device__ __forceinline__ void cvt_regs(const f32x4 f0, const f32x4 f1,
                                         s16x8* hi, s16x8* lo) {
    i32x4 h, l;
    h[0] = cvtpk(f0[0], f0[1]); h[1] = cvtpk(f0[2], f0[3]);
    h[2] = cvtpk(f1[0], f1[1]); h[3] = cvtpk(f1[2], f1[3]);
    l[0] = cvtpk(f0[0] - __builtin_bit_cast(float, h[0] << 16),
                 f0[1] - __builtin_bit_cast(float, h[0] & 0xffff0000));
    l[1] = cvtpk(f0[2] - __builtin_bit_cast(float, h[1] << 16),
                 f0[3] - __builtin_bit_cast(float, h[1] & 0xffff0000));
    l[2] = cvtpk(f1[0] - __builtin_bit_cast(float, h[2] << 16),
                 f1[1] - __builtin_bit_cast(float, h[2] & 0xffff0000));
    l[3] = cvtpk(f1[2] - __builtin_bit_cast(float, h[3] << 16),
                 f1[3] - __builtin_bit_cast(float, h[3] & 0xffff0000));
    *hi = __builtin_bit_cast(s16x8, h);
    *lo = __builtin_bit_cast(s16x8, l);
}

// ---------------- W -> fragment-major bf16 hi/lo (proven r11-13) ----------------
__global__ __launch_bounds__(256) void frag_kernel(
        const float* __restrict__ M,
        unsigned short* __restrict__ Fhi, unsigned short* __restrict__ Flo) {
    const int task = blockIdx.x * 4 + (threadIdx.x >> 6);
    const int lane = threadIdx.x & 63;
    const int rowblk = task >> 5;
    const int kstep  = task & 31;
    const float* src = M + (size_t)(rowblk * 16 + (lane & 15)) * ED
                         + kstep * 32 + (lane >> 4) * 8;
    const f32x4 f0 = *(const f32x4*)src;
    const f32x4 f1 = *(const f32x4*)(src + 4);
    s16x8 h, l;
    cvt_regs(f0, f1, &h, &l);
    const size_t o = ((size_t)task * 64 + lane) * 8;
    *(s16x8*)&Fhi[o] = h;
    *(s16x8*)&Flo[o] = l;
}

// ---------------- asm-forced-pipeline MFMA GEMM ----------------
// Zero LDS, zero barriers. Loads are asm volatile (cannot be re-sunk -> true
// 1-step prefetch, unlike r5/r6/r12 where the compiler collapsed the pipeline,
// VGPR 88-96 evidence). Counted s_waitcnt vmcnt(16) + sched_barrier(0) gates
// each MFMA cluster (rule #18). A read straight from X fp32 (per-lane frag
// addressing) + cvt-in-reg AFTER the wait; B from fragment-major Wfrag
// (L2-resident 4MB). 16 loads per K-step per wave (8 A fp32 + 8 B bf16).
#define GLOADF(dst, ptr) \
    asm volatile("global_load_dwordx4 %0, %1, off" : "=v"(dst) : "v"(ptr))
#define GLOADS(dst, ptr) \
    asm volatile("global_load_dwordx4 %0, %1, off" : "=v"(dst) : "v"(ptr))
#define WAIT16() do { asm volatile("s_waitcnt vmcnt(16)" ::: "memory"); \
                      __builtin_amdgcn_sched_barrier(0); } while (0)
#define WAIT0()  do { asm volatile("s_waitcnt vmcnt(0)" ::: "memory");  \
                      __builtin_amdgcn_sched_barrier(0); } while (0)

__global__ __launch_bounds__(256, 2) void gemm_asm_kernel(
        const float* __restrict__ Xf,
        const unsigned short* __restrict__ Bhi, const unsigned short* __restrict__ Blo,
        float* __restrict__ C) {
    // bm-major XCD swizzle: each XCD owns 8 bm strips (X 4MB + Wfrag 4MB L2-resident)
    const int bid = blockIdx.x;
    const int xcd = bid & 7;
    const int j   = bid >> 3;
    const int bm  = xcd * 8 + (j >> 3);   // 0..63
    const int bn  = j & 7;                // 0..7

    const int lane = threadIdx.x & 63;
    const int wid  = threadIdx.x >> 6;
    const int wm = wid >> 1, wn = wid & 1;
    const int fr = lane & 15, fg = lane >> 4;

    // A: lane reads X[bm*128 + wm*64 + i*16 + fr][T*32 + fg*8 ..+8)
    const float* gA = Xf + (size_t)(bm * 128 + wm * 64 + fr) * ED + fg * 8;
    // B: fragment-major (proven r12): rowblk = bn*8 + wn*4 + i
    const unsigned short* gBh = Bhi + (size_t)(bn * 8 + wn * 4) * 16384 + (size_t)lane * 8;
    const unsigned short* gBl = Blo + (size_t)(bn * 8 + wn * 4) * 16384 + (size_t)lane * 8;

    f32x4 aR0[8], aR1[8];
    s16x8 bh0[4], bl0[4], bh1[4], bl1[4];

#define LOADALL(S, T)                                                       \
    {                                                                       \
        _Pragma("unroll")                                                   \
        for (int i = 0; i < 4; ++i) {                                       \
            const float* p = gA + (size_t)(i * 16) * ED + (T) * 32;         \
            GLOADF(aR##S[2 * i],     p);                                    \
            GLOADF(aR##S[2 * i + 1], p + 4);                                \
        }                                                                   \
        _Pragma("unroll")                                                   \
        for (int i = 0; i < 4; ++i) {                                       \
            GLOADS(bh##S[i], gBh + i * 16384 + (T) * 512);                  \
            GLOADS(bl##S[i], gBl + i * 16384 + (T) * 512);                  \
        }                                                                   \
    }

#define COMPUTE(S)                                                          \
    {                                                                       \
        s16x8 ah[4], al[4];                                                 \
        _Pragma("unroll")                                                   \
        for (int i = 0; i < 4; ++i)                                         \
            cvt_regs(aR##S[2 * i], aR##S[2 * i + 1], &ah[i], &al[i]);       \
        _Pragma("unroll")                                                   \
        for (int i = 0; i < 4; ++i)                                         \
            _Pragma("unroll")                                               \
            for (int jj = 0; jj < 4; ++jj) {                                \
                acc[i][jj] = __builtin_amdgcn_mfma_f32_16x16x32_bf16(ah[i], bh##S[jj], acc[i][jj], 0, 0, 0); \
                acc[i][jj] = __builtin_amdgcn_mfma_f32_16x16x32_bf16(ah[i], bl##S[jj], acc[i][jj], 0, 0, 0); \
                acc[i][jj] = __builtin_amdgcn_mfma_f32_16x16x32_bf16(al[i], bh##S[jj], acc[i][jj], 0, 0, 0); \
            }                                                               \
    }

    f32x4 acc[4][4] = {};

    LOADALL(0, 0);                         // 16 outstanding
    for (int t2 = 0; t2 < 30; t2 += 2) {
        LOADALL(1, t2 + 1);                // 32 outstanding
        WAIT16();                          // set0 landed
        COMPUTE(0);
        LOADALL(0, t2 + 2);                // 32 outstanding
        WAIT16();                          // set1 landed
        COMPUTE(1);
    }
    // t2 = 30: set0 holds step 30 (16 outstanding)
    LOADALL(1, 31);
    WAIT16();
    COMPUTE(0);                            // step 30
    WAIT0();
    COMPUTE(1);                            // step 31
#undef LOADALL
#undef COMPUTE

    const int crow = bm * 128 + wm * 64 + fg * 4;
    const int ccol = bn * 128 + wn * 64 + fr;
#pragma unroll
    for (int i = 0; i < 4; ++i)
#pragma unroll
        for (int jj = 0; jj < 4; ++jj)
#pragma unroll
            for (int r = 0; r < 4; ++r)
                C[(size_t)(crow + i * 16 + r) * ED + ccol + jj * 16] = acc[i][jj][r];
}

// ---------------- fp32 fallback GEMM ----------------
#define BM 128
#define BN 128
#define BK 32
#define LDA (BM + 4)
#define LDB (BN + 4)

__global__ __launch_bounds__(256) void gemm_logits_kernel(const float* __restrict__ X,
                                                          const float* __restrict__ W,
                                                          float* __restrict__ C) {
    __shared__ float As[BK][LDA];
    __shared__ float Bs[BK][LDB];
    const int bm  = blockIdx.y * BM;
    const int bn  = blockIdx.x * BN;
    const int tid = threadIdx.x;
    const int tx  = tid & 15;
    const int ty  = tid >> 4;
    const int lr  = tid >> 3;
    const int lc  = (tid & 7) << 2;

    float acc[8][8];
#pragma unroll
    for (int i = 0; i < 8; ++i)
#pragma unroll
        for (int j = 0; j < 8; ++j) acc[i][j] = 0.f;

    for (int k0 = 0; k0 < ED; k0 += BK) {
#pragma unroll
        for (int i = 0; i < 4; ++i) {
            const int r = lr + i * 32;
            float4 va = *(const float4*)&X[(size_t)(bm + r) * ED + k0 + lc];
            As[lc + 0][r] = va.x; As[lc + 1][r] = va.y;
            As[lc + 2][r] = va.z; As[lc + 3][r] = va.w;
            float4 vb = *(const float4*)&W[(size_t)(bn + r) * ED + k0 + lc];
            Bs[lc + 0][r] = vb.x; Bs[lc + 1][r] = vb.y;
            Bs[lc + 2][r] = vb.z; Bs[lc + 3][r] = vb.w;
        }
        __syncthreads();
#pragma unroll
        for (int kk = 0; kk < BK; ++kk) {
            float a[8], b[8];
            *(float4*)&a[0] = *(const float4*)&As[kk][ty * 8];
            *(float4*)&a[4] = *(const float4*)&As[kk][ty * 8 + 4];
            *(float4*)&b[0] = *(const float4*)&Bs[kk][tx * 8];
            *(float4*)&b[4] = *(const float4*)&Bs[kk][tx * 8 + 4];
#pragma unroll
            for (int i = 0; i < 8; ++i)
#pragma unroll
                for (int j = 0; j < 8; ++j)
                    acc[i][j] = fmaf(a[i], b[j], acc[i][j]);
        }
        __syncthreads();
    }
#pragma unroll
    for (int i = 0; i < 8; ++i) {
        const int r = bm + ty * 8 + i;
        float4* dst = (float4*)&C[(size_t)r * ED + bn + tx * 8];
        dst[0] = make_float4(acc[i][0], acc[i][1], acc[i][2], acc[i][3]);
        dst[1] = make_float4(acc[i][4], acc[i][5], acc[i][6], acc[i][7]);
    }
}

__device__ __forceinline__ bool better(float v, int i, float bv, int bi) {
    return (v > bv) || (v == bv && i < bi);
}

// ------------- one wave per token, barrier-free softmax/top2/y (proven r3) -----
__global__ __launch_bounds__(256, 8) void softmax_wave_kernel(
        const float* __restrict__ X, float* __restrict__ OUT,
        float* __restrict__ partial, int* __restrict__ counts) {
    __shared__ float L[4 * 1024];
    const int tid  = threadIdx.x;
    const int lane = tid & 63;
    const int w    = tid >> 6;
    const int t    = blockIdx.x * 4 + w;

    const float4* row4 = (const float4*)&OUT[(size_t)t * ED];
    float4 p[4];
#pragma unroll
    for (int i = 0; i < 4; ++i) p[i] = row4[lane + 64 * i];

    float v1 = -1e30f, v2 = -1e30f; int i1 = 0x7fffffff, i2 = 0x7fffffff;
#pragma unroll
    for (int i = 0; i < 4; ++i) {
        const float vv[4] = {p[i].x, p[i].y, p[i].z, p[i].w};
#pragma unroll
        for (int c = 0; c < 4; ++c) {
            const int e = 256 * i + 4 * lane + c;
            const float v = vv[c];
            if (better(v, e, v1, i1)) { v2 = v1; i2 = i1; v1 = v; i1 = e; }
            else if (better(v, e, v2, i2)) { v2 = v; i2 = e; }
        }
    }
#pragma unroll
    for (int off = 32; off; off >>= 1) {
        const float ov1 = __shfl_xor(v1, off); const int oi1 = __shfl_xor(i1, off);
        const float ov2 = __shfl_xor(v2, off); const int oi2 = __shfl_xor(i2, off);
        if (better(ov1, oi1, v1, i1)) {
            float nv2; int ni2;
            if (better(v1, i1, ov2, oi2)) { nv2 = v1; ni2 = i1; }
            else { nv2 = ov2; ni2 = oi2; }
            v1 = ov1; i1 = oi1; v2 = nv2; i2 = ni2;
        } else if (better(ov1, oi1, v2, i2)) { v2 = ov1; i2 = oi1; }
    }
    const float m = v1;

    float s = 0.f;
#pragma unroll
    for (int i = 0; i < 4; ++i) {
        p[i].x = __expf(p[i].x - m); p[i].y = __expf(p[i].y - m);
        p[i].z = __expf(p[i].z - m); p[i].w = __expf(p[i].w - m);
        s += p[i].x + p[i].y + p[i].z + p[i].w;
    }
#pragma unroll
    for (int off = 32; off; off >>= 1) s += __shfl_xor(s, off);
    const float inv = 1.f / s;

#pragma unroll
    for (int i = 0; i < 4; ++i) {
        float4 q = make_float4(p[i].x * inv, p[i].y * inv, p[i].z * inv, p[i].w * inv);
        *(float4*)&L[w * 1024 + i * 256 + lane * 4] = q;
    }

    const float p1 = inv;
    const float p2 = __expf(v2 - m) * inv;
    const int b = t >> 10;
    const float4* x1 = (const float4*)&X[((size_t)(b << 10) + i1) * ED];
    const float4* x2 = (const float4*)&X[((size_t)(b << 10) + i2) * ED];
    float4* yrow = (float4*)&OUT[(size_t)t * ED];
#pragma unroll
    for (int i = 0; i < 4; ++i) {
        const int idx = lane + 64 * i;
        const float4 a = x1[idx];
        const float4 c = x2[idx];
        float4 r;
        r.x = fmaf(p1, a.x, p2 * c.x);
        r.y = fmaf(p1, a.y, p2 * c.y);
        r.z = fmaf(p1, a.z, p2 * c.z);
        r.w = fmaf(p1, a.w, p2 * c.w);
        yrow[idx] = r;
    }

    if (lane == 0) { atomicAdd(&counts[i1], 1); atomicAdd(&counts[i2], 1); }

    __syncthreads();
    float4 s0 = *(float4*)&L[0 * 1024 + tid * 4];
    float4 s1 = *(float4*)&L[1 * 1024 + tid * 4];
    float4 s2 = *(float4*)&L[2 * 1024 + tid * 4];
    float4 s3 = *(float4*)&L[3 * 1024 + tid * 4];
    float4 r;
    r.x = (s0.x + s1.x) + (s2.x + s3.x);
    r.y = (s0.y + s1.y) + (s2.y + s3.y);
    r.z = (s0.z + s1.z) + (s2.z + s3.z);
    r.w = (s0.w + s1.w) + (s2.w + s3.w);
    *(float4*)&partial[(size_t)blockIdx.x * 1024 + tid * 4] = r;
}

// ---------------- aux: deterministic two-stage reduction (2048 partials) -------
__global__ __launch_bounds__(256) void aux1_kernel(const float* __restrict__ partial,
                                                   const int* __restrict__ counts,
                                                   float* __restrict__ dotPartial) {
    __shared__ float red[16][16];
    const int tid = threadIdx.x;
    const int el  = tid & 15;
    const int ch  = tid >> 4;
    const int e   = blockIdx.x * 16 + el;
    float s = 0.f;
    for (int k = 0; k < 128; ++k)
        s += partial[(size_t)(ch * 128 + k) * 1024 + e];
    red[ch][el] = s;
    __syncthreads();
    if (tid < 16) {
        float rs = 0.f;
#pragma unroll
        for (int c = 0; c < 16; ++c) rs += red[c][tid];
        float val = rs * (float)counts[blockIdx.x * 16 + tid];
#pragma unroll
        for (int off = 8; off; off >>= 1) val += __shfl_xor(val, off);
        if (tid == 0) dotPartial[blockIdx.x] = val;
    }
}

__global__ void aux2_kernel(const float* __restrict__ dotPartial, float* __restrict__ out) {
    const int lane = threadIdx.x;
    float v = dotPartial[lane];
#pragma unroll
    for (int off = 32; off; off >>= 1) v += __shfl_xor(v, off);
    if (lane == 0)
        out[(size_t)MTOK * ED] = v * (0.01f * 1024.f / (8192.f * 16384.f));
}

// ---------------- fallback softmax (proven round-1 path) ----------------
#define TOKS_PER_BLK 16
__global__ __launch_bounds__(256) void softmax_topk_y_kernel(
        const float* __restrict__ X, float* __restrict__ OUT,
        float* __restrict__ router_sum, int* __restrict__ counts) {
    __shared__ float routerLocal[ED];
    __shared__ float redMax[4];
    __shared__ float redSum[4];
    __shared__ float wV1[4]; __shared__ int wI1[4];
    __shared__ float wV2[4]; __shared__ int wI2[4];

    const int tid  = threadIdx.x;
    const int lane = tid & 63;
    const int wave = tid >> 6;

    for (int e = tid; e < ED; e += 256) routerLocal[e] = 0.f;
    __syncthreads();

    const int t0 = blockIdx.x * TOKS_PER_BLK;
    for (int t = t0; t < t0 + TOKS_PER_BLK; ++t) {
        const float* lrow = &OUT[(size_t)t * ED];
        float l[4];
#pragma unroll
        for (int i = 0; i < 4; ++i) l[i] = lrow[tid + i * 256];

        float m = fmaxf(fmaxf(l[0], l[1]), fmaxf(l[2], l[3]));
#pragma unroll
        for (int off = 32; off; off >>= 1) m = fmaxf(m, __shfl_xor(m, off));
        if (lane == 0) redMax[wave] = m;
        __syncthreads();
        m = fmaxf(fmaxf(redMax[0], redMax[1]), fmaxf(redMax[2], redMax[3]));

        float p[4]; float s = 0.f;
#pragma unroll
        for (int i = 0; i < 4; ++i) { p[i] = expf(l[i] - m); s += p[i]; }
#pragma unroll
        for (int off = 32; off; off >>= 1) s += __shfl_xor(s, off);
        if (lane == 0) redSum[wave] = s;

        float v1 = -1e30f, v2 = -1e30f; int i1 = 0x7fffffff, i2 = 0x7fffffff;
#pragma unroll
        for (int i = 0; i < 4; ++i) {
            const float v = l[i]; const int ix = tid + i * 256;
            if (better(v, ix, v1, i1)) { v2 = v1; i2 = i1; v1 = v; i1 = ix; }
            else if (better(v, ix, v2, i2)) { v2 = v; i2 = ix; }
        }
#pragma unroll
        for (int off = 32; off; off >>= 1) {
            const float ov1 = __shfl_xor(v1, off); const int oi1 = __shfl_xor(i1, off);
            const float ov2 = __shfl_xor(v2, off); const int oi2 = __shfl_xor(i2, off);
            if (better(ov1, oi1, v1, i1)) {
                float nv2; int ni2;
                if (better(v1, i1, ov2, oi2)) { nv2 = v1; ni2 = i1; }
                else { nv2 = ov2; ni2 = oi2; }
                v1 = ov1; i1 = oi1; v2 = nv2; i2 = ni2;
            } else if (better(ov1, oi1, v2, i2)) { v2 = ov1; i2 = oi1; }
        }
        if (lane == 0) { wV1[wave] = v1; wI1[wave] = i1; wV2[wave] = v2; wI2[wave] = i2; }
        __syncthreads();

        v1 = wV1[0]; i1 = wI1[0]; v2 = wV2[0]; i2 = wI2[0];
#pragma unroll
        for (int w = 1; w < 4; ++w) {
            const float ov1 = wV1[w]; const int oi1 = wI1[w];
            const float ov2 = wV2[w]; const int oi2 = wI2[w];
            if (better(ov1, oi1, v1, i1)) {
                float nv2; int ni2;
                if (better(v1, i1, ov2, oi2)) { nv2 = v1; ni2 = i1; }
                else { nv2 = ov2; ni2 = oi2; }
                v1 = ov1; i1 = oi1; v2 = nv2; i2 = ni2;
            } else if (better(ov1, oi1, v2, i2)) { v2 = ov1; i2 = oi1; }
        }
        const float stot = redSum[0] + redSum[1] + redSum[2] + redSum[3];
        const float inv = 1.f / stot;

#pragma unroll
        for (int i = 0; i < 4; ++i) routerLocal[tid + i * 256] += p[i] * inv;

        const float p1 = expf(v1 - m) * inv;
        const float p2 = expf(v2 - m) * inv;

        const int b = t >> 10;
        const float4* x1 = (const float4*)&X[((size_t)(b << 10) + i1) * ED];
        const float4* x2 = (const float4*)&X[((size_t)(b << 10) + i2) * ED];
        float4* yrow = (float4*)&OUT[(size_t)t * ED];
        const float4 a = x1[tid];
        const float4 c = x2[tid];
        float4 r;
        r.x = fmaf(p1, a.x, p2 * c.x);
        r.y = fmaf(p1, a.y, p2 * c.y);
        r.z = fmaf(p1, a.z, p2 * c.z);
        r.w = fmaf(p1, a.w, p2 * c.w);
        yrow[tid] = r;

        if (tid == 0) { atomicAdd(&counts[i1], 1); atomicAdd(&counts[i2], 1); }
        __syncthreads();
    }

    for (int e = tid; e < ED; e += 256) atomicAdd(&router_sum[e], routerLocal[e]);
}

__global__ __launch_bounds__(256) void aux_kernel(const float* __restrict__ router_sum,
                                                  const int* __restrict__ counts,
                                                  float* __restrict__ out) {
    __shared__ float red[4];
    const int tid = threadIdx.x;
    float s = 0.f;
    for (int e = tid; e < ED; e += 256)
        s += (router_sum[e] * (1.f / 8192.f)) * ((float)counts[e] * (1.f / 16384.f));
#pragma unroll
    for (int off = 32; off; off >>= 1) s += __shfl_xor(s, off);
    if ((tid & 63) == 0) red[tid >> 6] = s;
    __syncthreads();
    if (tid == 0) out[(size_t)MTOK * ED] = 0.01f * 1024.f * (red[0] + red[1] + red[2] + red[3]);
}

// ---------------- launch ----------------
extern "C" void kernel_launch(void* const* d_in, const int* in_sizes, int n_in,
                              void* d_out, int out_size, void* d_ws, size_t ws_size,
                              hipStream_t stream) {
    const float* X = (const float*)d_in[0];   // (B,S,D) fp32
    const float* W = (const float*)d_in[1];   // (E,D)  fp32
    float* out = (float*)d_out;

    // ws: [Wfrag hi 2MB][Wfrag lo 2MB][partial 2048x1024 f32 8MB][dot 256B][counts 4KB]
    const size_t WS_NEED = (size_t)ED * ED * 2 * sizeof(unsigned short)
                         + (size_t)2048 * 1024 * sizeof(float)
                         + 64 * sizeof(float) + ED * sizeof(int);

    if (ws_size >= WS_NEED) {
        unsigned short* Wfh = (unsigned short*)d_ws;
        unsigned short* Wfl = Wfh + (size_t)ED * ED;
        float* partial      = (float*)(Wfl + (size_t)ED * ED);   // [2048][1024]
        float* dotPartial   = partial + (size_t)2048 * 1024;     // 64 floats
        int*   counts       = (int*)(dotPartial + 64);           // 1024 ints

        hipMemsetAsync(counts, 0, ED * sizeof(int), stream);
        frag_kernel<<<512, 256, 0, stream>>>(W, Wfh, Wfl);
        gemm_asm_kernel<<<512, 256, 0, stream>>>(X, Wfh, Wfl, out);
        softmax_wave_kernel<<<MTOK / 4, 256, 0, stream>>>(X, out, partial, counts);
        aux1_kernel<<<64, 256, 0, stream>>>(partial, counts, dotPartial);
        aux2_kernel<<<1, 64, 0, stream>>>(dotPartial, out);
    } else {
        float* router_sum = (float*)d_ws;
        int*   counts     = (int*)((char*)d_ws + ED * sizeof(float));
        hipMemsetAsync(d_ws, 0, ED * (sizeof(float) + sizeof(int)), stream);
        dim3 ggrid(ED / BN, MTOK / BM);
        gemm_logits_kernel<<<ggrid, 256, 0, stream>>>(X, W, out);
        softmax_topk_y_kernel<<<MTOK / TOKS_PER_BLK, 256, 0, stream>>>(X, out, router_sum, counts);
        aux_kernel<<<1, 256, 0, stream>>>(router_sum, counts, out);
    }
}

// Round 15
// 90.593 us; speedup vs baseline: 1.3177x; 1.3177x over previous
//
#include <hip/hip_runtime.h>

#define MTOK 8192   // B*S tokens
#define ED   1024   // E == D == 1024

typedef short s16x8 __attribute__((ext_vector_type(8)));
typedef float f32x4 __attribute__((ext_vector_type(4)));
typedef int   i32x4 __attribute__((ext_vector_type(4)));
typedef unsigned short u16x4 __attribute__((ext_vector_type(4)));

__device__ __forceinline__ unsigned short f2bf(float f) {
    unsigned u = __builtin_bit_cast(unsigned, f);
    u += 0x7fff + ((u >> 16) & 1);          // RNE
    return (unsigned short)(u >> 16);
}
__device__ __forceinline__ float bf2f(unsigned short h) {
    unsigned u = ((unsigned)h) << 16;
    return __builtin_bit_cast(float, u);
}

// ---------------- split fp32 -> bf16 hi + bf16 lo (W only); block 0 also zeroes counts
__global__ __launch_bounds__(256) void split_bf16_kernel(
        const float* __restrict__ src, unsigned short* __restrict__ hi,
        unsigned short* __restrict__ lo, int* __restrict__ counts, int n4) {
    if (blockIdx.x == 0) {
#pragma unroll
        for (int i = 0; i < 4; ++i) counts[threadIdx.x + i * 256] = 0;
    }
    int idx = blockIdx.x * 256 + threadIdx.x;
    const int stride = gridDim.x * 256;
    for (; idx < n4; idx += stride) {
        float4 v = ((const float4*)src)[idx];
        u16x4 h, l;
        h[0] = f2bf(v.x); l[0] = f2bf(v.x - bf2f(h[0]));
        h[1] = f2bf(v.y); l[1] = f2bf(v.y - bf2f(h[1]));
        h[2] = f2bf(v.z); l[2] = f2bf(v.z - bf2f(h[2]));
        h[3] = f2bf(v.w); l[3] = f2bf(v.w - bf2f(h[3]));
        ((u16x4*)hi)[idx] = h;
        ((u16x4*)lo)[idx] = l;
    }
}

// ---------------- MFMA split GEMM: C[M,E] = X[M,D] * W[E,D]^T ----------------
// X staged global->REG (fp32) at phase start; converted to bf16 hi/lo and
// ds_written into the next LDS buffer AFTER the MFMA cluster (T14). LDS layout
// and read path bit-identical to the proven round-4 kernel (0 conflicts):
// per buffer [Ahi 8K][Alo 8K][Bhi 8K][Blo 8K]; chunk c at c*1024B, slot l holds
// row c*16+(l>>2), k=sg(l)*8, sg(l)=(l&3)^((l>>3)&3); read pg = fg^((fr>>1)&3).
// Best-measured configuration: 66 us GEMM, 93.7 us total (round 10).
__device__ __forceinline__ void gload16(const void* g, void* l) {
    __builtin_amdgcn_global_load_lds(
        (const __attribute__((address_space(1))) void*)g,
        (__attribute__((address_space(3))) void*)l, 16, 0, 0);
}

__device__ __forceinline__ int cvtpk(float a, float b) {
    int r;
    asm("v_cvt_pk_bf16_f32 %0, %1, %2" : "=v"(r) : "v"(a), "v"(b));
    return r;
}

__device__ __forceinline__ void cvt_write(void* dstHi, void* dstLo,
                                          const float4 f0, const float4 f1) {
    i32x4 h, l;
    h[0] = cvtpk(f0.x, f0.y); h[1] = cvtpk(f0.z, f0.w);
    h[2] = cvtpk(f1.x, f1.y); h[3] = cvtpk(f1.z, f1.w);
    l[0] = cvtpk(f0.x - __builtin_bit_cast(float, h[0] << 16),
                 f0.y - __builtin_bit_cast(float, h[0] & 0xffff0000));
    l[1] = cvtpk(f0.z - __builtin_bit_cast(float, h[1] << 16),
                 f0.w - __builtin_bit_cast(float, h[1] & 0xffff0000));
    l[2] = cvtpk(f1.x - __builtin_bit_cast(float, h[2] << 16),
                 f1.y - __builtin_bit_cast(float, h[2] & 0xffff0000));
    l[3] = cvtpk(f1.z - __builtin_bit_cast(float, h[3] << 16),
                 f1.w - __builtin_bit_cast(float, h[3] & 0xffff0000));
    *(i32x4*)dstHi = h;
    *(i32x4*)dstLo = l;
}

__global__ __launch_bounds__(256, 2) void gemm_mfma_split_kernel(
        const float* __restrict__ Xf,
        const unsigned short* __restrict__ Whi, const unsigned short* __restrict__ Wlo,
        float* __restrict__ C) {
    __shared__ __align__(16) unsigned char smem[2 * 32768];  // 64 KB

    // bm-major XCD swizzle: each XCD owns 8 consecutive bm tiles (4 MB X strip)
    const int bid = blockIdx.x;
    const int xcd = bid & 7;
    const int j   = bid >> 3;
    const int bm  = xcd * 8 + (j >> 3);
    const int bn  = j & 7;

    const int tid  = threadIdx.x;
    const int lane = tid & 63;
    const int wid  = tid >> 6;

    // staging maps (same (row,k) <-> slot map as round 4)
    const int srow = lane >> 2;                       // 0..15
    const int sg   = (lane & 3) ^ ((lane >> 3) & 3);  // k-group swizzle
    // A: wave w owns chunks {2w, 2w+1} (rows w*32 .. w*32+31), fp32 -> regs
    const float* gA = Xf + (size_t)(bm * 128 + wid * 32 + srow) * ED + sg * 8;
    // B: waves 0,1 stage Bhi; waves 2,3 stage Blo; 4 chunks each via gload_lds
    const unsigned short* gB = ((wid < 2) ? Whi : Wlo)
            + (size_t)(bn * 128 + (wid & 1) * 64 + srow) * ED + sg * 8;
    unsigned char* const dB = smem + 16384 + ((wid < 2) ? 0 : 8192) + (wid & 1) * 4096;

    float4 fA0, fA1, fA2, fA3;

#define ALOAD(kk)                                                    \
    fA0 = *(const float4*)(gA + (kk));                               \
    fA1 = *(const float4*)(gA + (kk) + 4);                           \
    fA2 = *(const float4*)(gA + (kk) + 16 * 1024);                   \
    fA3 = *(const float4*)(gA + (kk) + 16 * 1024 + 4);

#define BSTAGE(buf, kk)                                              \
    _Pragma("unroll")                                                \
    for (int c = 0; c < 4; ++c)                                      \
        gload16(gB + (kk) + c * (16 * ED), dB + (buf) * 32768 + c * 1024);

#define AWRITE(buf)                                                              \
    cvt_write(smem + (buf) * 32768 + (2 * wid) * 1024 + lane * 16,               \
              smem + (buf) * 32768 + 8192 + (2 * wid) * 1024 + lane * 16,        \
              fA0, fA1);                                                         \
    cvt_write(smem + (buf) * 32768 + (2 * wid + 1) * 1024 + lane * 16,           \
              smem + (buf) * 32768 + 8192 + (2 * wid + 1) * 1024 + lane * 16,    \
              fA2, fA3);

    // fragment read setup (round-4 path, XOR-deswizzle)
    const int wm = wid >> 1, wn = wid & 1;
    const int fr = lane & 15, fg = lane >> 4;
    const int pg = fg ^ ((fr >> 1) & 3);
    const int aoff = (wm * 64 + fr) * 32 + pg * 8;   // elements in Ahi/Alo
    const int boff = (wn * 64 + fr) * 32 + pg * 8;   // elements in Bhi/Blo

    f32x4 acc[4][4] = {};

    // prologue: tile 0
    ALOAD(0);
    BSTAGE(0, 0);
    AWRITE(0);   // compiler inserts vmcnt waits on the fA dependencies
    asm volatile("s_waitcnt vmcnt(0) lgkmcnt(0)" ::: "memory");
    __builtin_amdgcn_s_barrier();

    for (int t = 0; t < 32; ++t) {
        const int cur = t & 1;
        if (t < 31) { ALOAD((t + 1) * 32); BSTAGE(cur ^ 1, (t + 1) * 32); }

        const unsigned short* Ah = (const unsigned short*)(smem + cur * 32768);
        const unsigned short* Al = Ah + 4096;
        const unsigned short* Bh = Ah + 8192;
        const unsigned short* Bl = Ah + 12288;

        s16x8 ah[4], al[4], bh[4], bl[4];
#pragma unroll
        for (int i = 0; i < 4; ++i) {
            ah[i] = *(const s16x8*)&Ah[aoff + i * 512];
            al[i] = *(const s16x8*)&Al[aoff + i * 512];
            bh[i] = *(const s16x8*)&Bh[boff + i * 512];
            bl[i] = *(const s16x8*)&Bl[boff + i * 512];
        }
#pragma unroll
        for (int i = 0; i < 4; ++i)
#pragma unroll
            for (int jj = 0; jj < 4; ++jj) {
                acc[i][jj] = __builtin_amdgcn_mfma_f32_16x16x32_bf16(ah[i], bh[jj], acc[i][jj], 0, 0, 0);
                acc[i][jj] = __builtin_amdgcn_mfma_f32_16x16x32_bf16(ah[i], bl[jj], acc[i][jj], 0, 0, 0);
                acc[i][jj] = __builtin_amdgcn_mfma_f32_16x16x32_bf16(al[i], bh[jj], acc[i][jj], 0, 0, 0);
            }

        if (t < 31) AWRITE(cur ^ 1);   // write-late: cvt+ds_write after MFMA

        asm volatile("s_waitcnt vmcnt(0) lgkmcnt(0)" ::: "memory");
        __builtin_amdgcn_s_barrier();
    }
#undef ALOAD
#undef BSTAGE
#undef AWRITE

    const int crow = bm * 128 + wm * 64 + fg * 4;
    const int ccol = bn * 128 + wn * 64 + fr;
#pragma unroll
    for (int i = 0; i < 4; ++i)
#pragma unroll
        for (int jj = 0; jj < 4; ++jj)
#pragma unroll
            for (int r = 0; r < 4; ++r)
                C[(size_t)(crow + i * 16 + r) * ED + ccol + jj * 16] = acc[i][jj][r];
}

// ---------------- fp32 fallback GEMM ----------------
#define BM 128
#define BN 128
#define BK 32
#define LDA (BM + 4)
#define LDB (BN + 4)

__global__ __launch_bounds__(256) void gemm_logits_kernel(const float* __restrict__ X,
                                                          const float* __restrict__ W,
                                                          float* __restrict__ C) {
    __shared__ float As[BK][LDA];
    __shared__ float Bs[BK][LDB];
    const int bm  = blockIdx.y * BM;
    const int bn  = blockIdx.x * BN;
    const int tid = threadIdx.x;
    const int tx  = tid & 15;
    const int ty  = tid >> 4;
    const int lr  = tid >> 3;
    const int lc  = (tid & 7) << 2;

    float acc[8][8];
#pragma unroll
    for (int i = 0; i < 8; ++i)
#pragma unroll
        for (int j = 0; j < 8; ++j) acc[i][j] = 0.f;

    for (int k0 = 0; k0 < ED; k0 += BK) {
#pragma unroll
        for (int i = 0; i < 4; ++i) {
            const int r = lr + i * 32;
            float4 va = *(const float4*)&X[(size_t)(bm + r) * ED + k0 + lc];
            As[lc + 0][r] = va.x; As[lc + 1][r] = va.y;
            As[lc + 2][r] = va.z; As[lc + 3][r] = va.w;
            float4 vb = *(const float4*)&W[(size_t)(bn + r) * ED + k0 + lc];
            Bs[lc + 0][r] = vb.x; Bs[lc + 1][r] = vb.y;
            Bs[lc + 2][r] = vb.z; Bs[lc + 3][r] = vb.w;
        }
        __syncthreads();
#pragma unroll
        for (int kk = 0; kk < BK; ++kk) {
            float a[8], b[8];
            *(float4*)&a[0] = *(const float4*)&As[kk][ty * 8];
            *(float4*)&a[4] = *(const float4*)&As[kk][ty * 8 + 4];
            *(float4*)&b[0] = *(const float4*)&Bs[kk][tx * 8];
            *(float4*)&b[4] = *(const float4*)&Bs[kk][tx * 8 + 4];
#pragma unroll
            for (int i = 0; i < 8; ++i)
#pragma unroll
                for (int j = 0; j < 8; ++j)
                    acc[i][j] = fmaf(a[i], b[j], acc[i][j]);
        }
        __syncthreads();
    }
#pragma unroll
    for (int i = 0; i < 8; ++i) {
        const int r = bm + ty * 8 + i;
        float4* dst = (float4*)&C[(size_t)r * ED + bn + tx * 8];
        dst[0] = make_float4(acc[i][0], acc[i][1], acc[i][2], acc[i][3]);
        dst[1] = make_float4(acc[i][4], acc[i][5], acc[i][6], acc[i][7]);
    }
}

__device__ __forceinline__ bool better(float v, int i, float bv, int bi) {
    return (v > bv) || (v == bv && i < bi);
}

// ------------- one wave per token, barrier-free softmax/top2/y -------------
__global__ __launch_bounds__(256, 8) void softmax_wave_kernel(
        const float* __restrict__ X, float* __restrict__ OUT,
        float* __restrict__ partial, int* __restrict__ counts) {
    __shared__ float L[4 * 1024];
    const int tid  = threadIdx.x;
    const int lane = tid & 63;
    const int w    = tid >> 6;
    const int t    = blockIdx.x * 4 + w;          // token

    const float4* row4 = (const float4*)&OUT[(size_t)t * ED];
    float4 p[4];
#pragma unroll
    for (int i = 0; i < 4; ++i) p[i] = row4[lane + 64 * i];  // elem e = 256i+4*lane+c

    float v1 = -1e30f, v2 = -1e30f; int i1 = 0x7fffffff, i2 = 0x7fffffff;
#pragma unroll
    for (int i = 0; i < 4; ++i) {
        const float vv[4] = {p[i].x, p[i].y, p[i].z, p[i].w};
#pragma unroll
        for (int c = 0; c < 4; ++c) {
            const int e = 256 * i + 4 * lane + c;
            const float v = vv[c];
            if (better(v, e, v1, i1)) { v2 = v1; i2 = i1; v1 = v; i1 = e; }
            else if (better(v, e, v2, i2)) { v2 = v; i2 = e; }
        }
    }
#pragma unroll
    for (int off = 32; off; off >>= 1) {
        const float ov1 = __shfl_xor(v1, off); const int oi1 = __shfl_xor(i1, off);
        const float ov2 = __shfl_xor(v2, off); const int oi2 = __shfl_xor(i2, off);
        if (better(ov1, oi1, v1, i1)) {
            float nv2; int ni2;
            if (better(v1, i1, ov2, oi2)) { nv2 = v1; ni2 = i1; }
            else { nv2 = ov2; ni2 = oi2; }
            v1 = ov1; i1 = oi1; v2 = nv2; i2 = ni2;
        } else if (better(ov1, oi1, v2, i2)) { v2 = ov1; i2 = oi1; }
    }
    const float m = v1;   // top1 value IS the row max

    float s = 0.f;
#pragma unroll
    for (int i = 0; i < 4; ++i) {
        p[i].x = __expf(p[i].x - m); p[i].y = __expf(p[i].y - m);
        p[i].z = __expf(p[i].z - m); p[i].w = __expf(p[i].w - m);
        s += p[i].x + p[i].y + p[i].z + p[i].w;
    }
#pragma unroll
    for (int off = 32; off; off >>= 1) s += __shfl_xor(s, off);
    const float inv = 1.f / s;

#pragma unroll
    for (int i = 0; i < 4; ++i) {
        float4 q = make_float4(p[i].x * inv, p[i].y * inv, p[i].z * inv, p[i].w * inv);
        *(float4*)&L[w * 1024 + i * 256 + lane * 4] = q;
    }

    const float p1 = inv;                   // exp(v1-m)=1
    const float p2 = __expf(v2 - m) * inv;
    const int b = t >> 10;
    const float4* x1 = (const float4*)&X[((size_t)(b << 10) + i1) * ED];
    const float4* x2 = (const float4*)&X[((size_t)(b << 10) + i2) * ED];
    float4* yrow = (float4*)&OUT[(size_t)t * ED];
#pragma unroll
    for (int i = 0; i < 4; ++i) {
        const int idx = lane + 64 * i;
        const float4 a = x1[idx];
        const float4 c = x2[idx];
        float4 r;
        r.x = fmaf(p1, a.x, p2 * c.x);
        r.y = fmaf(p1, a.y, p2 * c.y);
        r.z = fmaf(p1, a.z, p2 * c.z);
        r.w = fmaf(p1, a.w, p2 * c.w);
        yrow[idx] = r;
    }

    if (lane == 0) { atomicAdd(&counts[i1], 1); atomicAdd(&counts[i2], 1); }

    __syncthreads();
    float4 s0 = *(float4*)&L[0 * 1024 + tid * 4];
    float4 s1 = *(float4*)&L[1 * 1024 + tid * 4];
    float4 s2 = *(float4*)&L[2 * 1024 + tid * 4];
    float4 s3 = *(float4*)&L[3 * 1024 + tid * 4];
    float4 r;
    r.x = (s0.x + s1.x) + (s2.x + s3.x);
    r.y = (s0.y + s1.y) + (s2.y + s3.y);
    r.z = (s0.z + s1.z) + (s2.z + s3.z);
    r.w = (s0.w + s1.w) + (s2.w + s3.w);
    *(float4*)&partial[(size_t)blockIdx.x * 1024 + tid * 4] = r;
}

// ---------------- aux: deterministic two-stage reduction ----------------
__global__ __launch_bounds__(256) void aux1_kernel(const float* __restrict__ partial,
                                                   const int* __restrict__ counts,
                                                   float* __restrict__ dotPartial) {
    __shared__ float red[16][16];
    const int tid = threadIdx.x;
    const int el  = tid & 15;
    const int ch  = tid >> 4;
    const int e   = blockIdx.x * 16 + el;
    float s = 0.f;
    for (int k = 0; k < 128; ++k)
        s += partial[(size_t)(ch * 128 + k) * 1024 + e];
    red[ch][el] = s;
    __syncthreads();
    if (tid < 16) {
        float rs = 0.f;
#pragma unroll
        for (int c = 0; c < 16; ++c) rs += red[c][tid];
        float val = rs * (float)counts[blockIdx.x * 16 + tid];
#pragma unroll
        for (int off = 8; off; off >>= 1) val += __shfl_xor(val, off);
        if (tid == 0) dotPartial[blockIdx.x] = val;
    }
}

__global__ void aux2_kernel(const float* __restrict__ dotPartial, float* __restrict__ out) {
    const int lane = threadIdx.x;
    float v = dotPartial[lane];
#pragma unroll
    for (int off = 32; off; off >>= 1) v += __shfl_xor(v, off);
    if (lane == 0)
        out[(size_t)MTOK * ED] = v * (0.01f * 1024.f / (8192.f * 16384.f));
}

// ---------------- fallback softmax (proven round-1 path) ----------------
#define TOKS_PER_BLK 16
__global__ __launch_bounds__(256) void softmax_topk_y_kernel(
        const float* __restrict__ X, float* __restrict__ OUT,
        float* __restrict__ router_sum, int* __restrict__ counts) {
    __shared__ float routerLocal[ED];
    __shared__ float redMax[4];
    __shared__ float redSum[4];
    __shared__ float wV1[4]; __shared__ int wI1[4];
    __shared__ float wV2[4]; __shared__ int wI2[4];

    const int tid  = threadIdx.x;
    const int lane = tid & 63;
    const int wave = tid >> 6;

    for (int e = tid; e < ED; e += 256) routerLocal[e] = 0.f;
    __syncthreads();

    const int t0 = blockIdx.x * TOKS_PER_BLK;
    for (int t = t0; t < t0 + TOKS_PER_BLK; ++t) {
        const float* lrow = &OUT[(size_t)t * ED];
        float l[4];
#pragma unroll
        for (int i = 0; i < 4; ++i) l[i] = lrow[tid + i * 256];

        float m = fmaxf(fmaxf(l[0], l[1]), fmaxf(l[2], l[3]));
#pragma unroll
        for (int off = 32; off; off >>= 1) m = fmaxf(m, __shfl_xor(m, off));
        if (lane == 0) redMax[wave] = m;
        __syncthreads();
        m = fmaxf(fmaxf(redMax[0], redMax[1]), fmaxf(redMax[2], redMax[3]));

        float p[4]; float s = 0.f;
#pragma unroll
        for (int i = 0; i < 4; ++i) { p[i] = expf(l[i] - m); s += p[i]; }
#pragma unroll
        for (int off = 32; off; off >>= 1) s += __shfl_xor(s, off);
        if (lane == 0) redSum[wave] = s;

        float v1 = -1e30f, v2 = -1e30f; int i1 = 0x7fffffff, i2 = 0x7fffffff;
#pragma unroll
        for (int i = 0; i < 4; ++i) {
            const float v = l[i]; const int ix = tid + i * 256;
            if (better(v, ix, v1, i1)) { v2 = v1; i2 = i1; v1 = v; i1 = ix; }
            else if (better(v, ix, v2, i2)) { v2 = v; i2 = ix; }
        }
#pragma unroll
        for (int off = 32; off; off >>= 1) {
            const float ov1 = __shfl_xor(v1, off); const int oi1 = __shfl_xor(i1, off);
            const float ov2 = __shfl_xor(v2, off); const int oi2 = __shfl_xor(i2, off);
            if (better(ov1, oi1, v1, i1)) {
                float nv2; int ni2;
                if (better(v1, i1, ov2, oi2)) { nv2 = v1; ni2 = i1; }
                else { nv2 = ov2; ni2 = oi2; }
                v1 = ov1; i1 = oi1; v2 = nv2; i2 = ni2;
            } else if (better(ov1, oi1, v2, i2)) { v2 = ov1; i2 = oi1; }
        }
        if (lane == 0) { wV1[wave] = v1; wI1[wave] = i1; wV2[wave] = v2; wI2[wave] = i2; }
        __syncthreads();

        v1 = wV1[0]; i1 = wI1[0]; v2 = wV2[0]; i2 = wI2[0];
#pragma unroll
        for (int w = 1; w < 4; ++w) {
            const float ov1 = wV1[w]; const int oi1 = wI1[w];
            const float ov2 = wV2[w]; const int oi2 = wI2[w];
            if (better(ov1, oi1, v1, i1)) {
                float nv2; int ni2;
                if (better(v1, i1, ov2, oi2)) { nv2 = v1; ni2 = i1; }
                else { nv2 = ov2; ni2 = oi2; }
                v1 = ov1; i1 = oi1; v2 = nv2; i2 = ni2;
            } else if (better(ov1, oi1, v2, i2)) { v2 = ov1; i2 = oi1; }
        }
        const float stot = redSum[0] + redSum[1] + redSum[2] + redSum[3];
        const float inv = 1.f / stot;

#pragma unroll
        for (int i = 0; i < 4; ++i) routerLocal[tid + i * 256] += p[i] * inv;

        const float p1 = expf(v1 - m) * inv;
        const float p2 = expf(v2 - m) * inv;

        const int b = t >> 10;
        const float4* x1 = (const float4*)&X[((size_t)(b << 10) + i1) * ED];
        const float4* x2 = (const float4*)&X[((size_t)(b << 10) + i2) * ED];
        float4* yrow = (float4*)&OUT[(size_t)t * ED];
        const float4 a = x1[tid];
        const float4 c = x2[tid];
        float4 r;
        r.x = fmaf(p1, a.x, p2 * c.x);
        r.y = fmaf(p1, a.y, p2 * c.y);
        r.z = fmaf(p1, a.z, p2 * c.z);
        r.w = fmaf(p1, a.w, p2 * c.w);
        yrow[tid] = r;

        if (tid == 0) { atomicAdd(&counts[i1], 1); atomicAdd(&counts[i2], 1); }
        __syncthreads();
    }

    for (int e = tid; e < ED; e += 256) atomicAdd(&router_sum[e], routerLocal[e]);
}

__global__ __launch_bounds__(256) void aux_kernel(const float* __restrict__ router_sum,
                                                  const int* __restrict__ counts,
                                                  float* __restrict__ out) {
    __shared__ float red[4];
    const int tid = threadIdx.x;
    float s = 0.f;
    for (int e = tid; e < ED; e += 256)
        s += (router_sum[e] * (1.f / 8192.f)) * ((float)counts[e] * (1.f / 16384.f));
#pragma unroll
    for (int off = 32; off; off >>= 1) s += __shfl_xor(s, off);
    if ((tid & 63) == 0) red[tid >> 6] = s;
    __syncthreads();
    if (tid == 0) out[(size_t)MTOK * ED] = 0.01f * 1024.f * (red[0] + red[1] + red[2] + red[3]);
}

// ---------------- launch ----------------
extern "C" void kernel_launch(void* const* d_in, const int* in_sizes, int n_in,
                              void* d_out, int out_size, void* d_ws, size_t ws_size,
                              hipStream_t stream) {
    const float* X = (const float*)d_in[0];   // (B,S,D) fp32
    const float* W = (const float*)d_in[1];   // (E,D)  fp32
    float* out = (float*)d_out;

    const size_t WS_NEED = (size_t)ED * ED * 2 * sizeof(unsigned short)   // Whi,Wlo 4MB
                         + (size_t)2048 * 1024 * sizeof(float)            // partial 8MB
                         + 64 * sizeof(float) + ED * sizeof(int);

    if (ws_size >= WS_NEED) {
        unsigned short* Whi = (unsigned short*)d_ws;
        unsigned short* Wlo = Whi + (size_t)ED * ED;
        float* partial      = (float*)(Wlo + (size_t)ED * ED);   // [2048][1024]
        float* dotPartial   = partial + (size_t)2048 * 1024;     // 64 floats
        int*   counts       = (int*)(dotPartial + 64);           // 1024 ints

        split_bf16_kernel<<<512, 256, 0, stream>>>(W, Whi, Wlo, counts, ED * ED / 4);
        gemm_mfma_split_kernel<<<512, 256, 0, stream>>>(X, Whi, Wlo, out);
        softmax_wave_kernel<<<MTOK / 4, 256, 0, stream>>>(X, out, partial, counts);
        aux1_kernel<<<64, 256, 0, stream>>>(partial, counts, dotPartial);
        aux2_kernel<<<1, 64, 0, stream>>>(dotPartial, out);
    } else {
        float* router_sum = (float*)d_ws;
        int*   counts     = (int*)((char*)d_ws + ED * sizeof(float));
        hipMemsetAsync(d_ws, 0, ED * (sizeof(float) + sizeof(int)), stream);
        dim3 ggrid(ED / BN, MTOK / BM);
        gemm_logits_kernel<<<ggrid, 256, 0, stream>>>(X, W, out);
        softmax_topk_y_kernel<<<MTOK / TOKS_PER_BLK, 256, 0, stream>>>(X, out, router_sum, counts);
        aux_kernel<<<1, 256, 0, stream>>>(router_sum, counts, out);
    }
}